// Round 9
// baseline (155.584 us; speedup 1.0000x reference)
//
#include <hip/hip_runtime.h>
#include <hip/hip_bf16.h>

#define LN_EPS 1e-5f

__device__ __forceinline__ float dot8(float4 a0, float4 a1, float4 b0, float4 b1) {
    return a0.x * b0.x + a0.y * b0.y + a0.z * b0.z + a0.w * b0.w +
           a1.x * b1.x + a1.y * b1.y + a1.z * b1.z + a1.w * b1.w;
}

__device__ __forceinline__ float rdlane(float v, int lane) {
    return __int_as_float(__builtin_amdgcn_readlane(__float_as_int(v), lane));
}

// ---------------------------------------------------------------------------
// Kernel 1: embed + pos + row attention (64 bins) + residual + LN
// one block per (b, s): 256 blocks x 256 threads
// Attention K/V live in per-lane registers (lane j holds K[j],V[j] slices);
// the j-loop broadcasts them via v_readlane (per-SIMD VALU pipe) instead of
// 256 ds_read_b128/wave on the shared per-CU DS pipe.
// ---------------------------------------------------------------------------
__global__ __launch_bounds__(256) void k_row(
    const float* __restrict__ ctcf, const float* __restrict__ hac,
    const float* __restrict__ me1,  const float* __restrict__ me3,
    const float* __restrict__ ew,   const float* __restrict__ eb,
    const float* __restrict__ pe,
    const float* __restrict__ w_in, const float* __restrict__ b_in,
    const float* __restrict__ w_out,const float* __restrict__ b_out,
    const float* __restrict__ ln_g, const float* __restrict__ ln_b,
    float* __restrict__ msaR)
{
    __shared__ float sx[64][33];        // x tile (residual source)
    __shared__ float sqkv[64 * 100];    // qkv rows, stride 100 (16B-aligned)
    __shared__ float so[64][33];        // attention output
    __shared__ float smean[64], srstd[64];

    const int blk = blockIdx.x;          // b*4 + s
    const int s   = blk & 3;
    const int b   = blk >> 2;
    const int tid = threadIdx.x;

    const float* chip = (s == 0) ? ctcf : (s == 1) ? hac : (s == 2) ? me1 : me3;

    for (int n = tid; n < 2048; n += 256) {
        int l = n >> 5, c = n & 31;
        sx[l][c] = chip[b * 64 + l] * ew[c] + eb[c] + pe[l * 32 + c];
    }
    __syncthreads();

    const int l  = tid & 63;
    const int cg = tid >> 6;             // wave id -> wave-uniform

    float xr[32];
#pragma unroll
    for (int c = 0; c < 32; ++c) xr[c] = sx[l][c];

    // qkv[l][cc] = x[l]·w_in[cc] + b_in[cc]; w row read from global (uniform)
#pragma unroll
    for (int i = 0; i < 24; ++i) {
        int cc = i * 4 + cg;
        const float4* wr4 = (const float4*)&w_in[cc * 32];
        float acc = b_in[cc];
#pragma unroll
        for (int c4 = 0; c4 < 8; ++c4) {
            float4 wv = wr4[c4];
            acc += xr[c4 * 4 + 0] * wv.x + xr[c4 * 4 + 1] * wv.y +
                   xr[c4 * 4 + 2] * wv.z + xr[c4 * 4 + 3] * wv.w;
        }
        sqkv[l * 100 + cc] = acc;
    }
    __syncthreads();

    // attention: thread (h = cg, lane = l). Gather own Q/K/V slices (6 b128),
    // then online softmax over j with readlane broadcasts (no DS traffic).
    {
        const int h = cg;
        const float4* qp = (const float4*)&sqkv[l * 100 + h * 8];
        float4 q0 = qp[0], q1 = qp[1];
        const float4* kp = (const float4*)&sqkv[l * 100 + 32 + h * 8];
        float4 kA = kp[0], kB = kp[1];
        const float4* vp = (const float4*)&sqkv[l * 100 + 64 + h * 8];
        float4 vA = vp[0], vB = vp[1];
        float kreg[8] = {kA.x, kA.y, kA.z, kA.w, kB.x, kB.y, kB.z, kB.w};
        float vreg[8] = {vA.x, vA.y, vA.z, vA.w, vB.x, vB.y, vB.z, vB.w};
        float q[8]    = {q0.x, q0.y, q0.z, q0.w, q1.x, q1.y, q1.z, q1.w};

        const float scale = 0.35355339059327373f;  // 1/sqrt(8)
        float mrun = -1e30f, denom = 0.f, a[8];
#pragma unroll
        for (int dd = 0; dd < 8; ++dd) a[dd] = 0.f;
#pragma unroll 8
        for (int j = 0; j < 64; ++j) {
            float sc = 0.f;
#pragma unroll
            for (int dd = 0; dd < 8; ++dd) sc += q[dd] * rdlane(kreg[dd], j);
            sc *= scale;
            float mnew = fmaxf(mrun, sc);
            float corr = __expf(mrun - mnew);
            float w = __expf(sc - mnew);
            denom = denom * corr + w;
#pragma unroll
            for (int dd = 0; dd < 8; ++dd)
                a[dd] = a[dd] * corr + w * rdlane(vreg[dd], j);
            mrun = mnew;
        }
        float inv = 1.f / denom;
#pragma unroll
        for (int dd = 0; dd < 8; ++dd) so[l][h * 8 + dd] = a[dd] * inv;
    }
    __syncthreads();

    // out proj + residual -> sqkv cols 0..31 (w row from global, uniform)
    {
        float orow[32];
#pragma unroll
        for (int k = 0; k < 32; ++k) orow[k] = so[l][k];
#pragma unroll
        for (int i = 0; i < 8; ++i) {
            int c = i * 4 + cg;
            const float4* wr4 = (const float4*)&w_out[c * 32];
            float acc = b_out[c] + xr[c];
#pragma unroll
            for (int k4 = 0; k4 < 8; ++k4) {
                float4 wv = wr4[k4];
                acc += orow[k4 * 4 + 0] * wv.x + orow[k4 * 4 + 1] * wv.y +
                       orow[k4 * 4 + 2] * wv.z + orow[k4 * 4 + 3] * wv.w;
            }
            sqkv[l * 100 + c] = acc;
        }
    }
    __syncthreads();

    if (tid < 64) {
        float mu = 0.f;
#pragma unroll
        for (int c = 0; c < 32; ++c) mu += sqkv[tid * 100 + c];
        mu *= (1.f / 32.f);
        float var = 0.f;
#pragma unroll
        for (int c = 0; c < 32; ++c) { float d = sqkv[tid * 100 + c] - mu; var += d * d; }
        var *= (1.f / 32.f);
        smean[tid] = mu;
        srstd[tid] = rsqrtf(var + LN_EPS);
    }
    __syncthreads();

    float* outp = msaR + blk * 2048;     // (B,S,Lb,C)
    for (int n = tid; n < 2048; n += 256) {
        int ll = n >> 5, c = n & 31;
        outp[n] = (sqkv[ll * 100 + c] - smean[ll]) * srstd[ll] * ln_g[c] + ln_b[c];
    }
}

// ---------------------------------------------------------------------------
// Kernel 2: column attention (4 tracks) + residual + LN + track mean + norm
// one block per (b, 16-bin chunk): 256 blocks x 256 threads
// Weights read directly from global (wave-uniform), token data in LDS.
// ---------------------------------------------------------------------------
__global__ __launch_bounds__(256) void k_col(
    const float* __restrict__ msaR,
    const float* __restrict__ w_in, const float* __restrict__ b_in,
    const float* __restrict__ w_out,const float* __restrict__ b_out,
    const float* __restrict__ ln_g, const float* __restrict__ ln_b,
    float* __restrict__ m_out, float* __restrict__ nrm_out)
{
    __shared__ float sx[64][33];        // rows keyed s*16+lo
    __shared__ float sqkv[64 * 100];    // rows keyed r = lo*4+s
    __shared__ float so[64][33];        // rows keyed r
    __shared__ float smean2[64], srstd2[64];
    __shared__ float smv[16][33];

    const int bx = blockIdx.x;           // 64 b x 4 chunks
    const int b  = bx >> 2;
    const int l0 = (bx & 3) * 16;
    const int tid = threadIdx.x;

    for (int n = tid; n < 2048; n += 256) {
        int s = n >> 9, lo = (n >> 5) & 15, c = n & 31;
        sx[s * 16 + lo][c] = msaR[((b * 4 + s) * 64 + l0 + lo) * 32 + c];
    }
    __syncthreads();

    const int r  = tid & 63;
    const int sS = r & 3, lo = r >> 2;
    const int cg = tid >> 6;

    float xr[32];
#pragma unroll
    for (int c = 0; c < 32; ++c) xr[c] = sx[sS * 16 + lo][c];

#pragma unroll
    for (int i = 0; i < 24; ++i) {
        int cc = i * 4 + cg;
        const float4* wr4 = (const float4*)&w_in[cc * 32];
        float acc = b_in[cc];
#pragma unroll
        for (int c4 = 0; c4 < 8; ++c4) {
            float4 wv = wr4[c4];
            acc += xr[c4 * 4 + 0] * wv.x + xr[c4 * 4 + 1] * wv.y +
                   xr[c4 * 4 + 2] * wv.z + xr[c4 * 4 + 3] * wv.w;
        }
        sqkv[r * 100 + cc] = acc;
    }
    __syncthreads();

    // attention over 4 tracks: thread (la = tid>>4, h = (tid>>2)&3, ia = tid&3)
    {
        const int la = tid >> 4, h = (tid >> 2) & 3, ia = tid & 3;
        const float scale = 0.35355339059327373f;
        const float4* qp = (const float4*)&sqkv[(la * 4 + ia) * 100 + h * 8];
        float4 q0 = qp[0], q1 = qp[1];
        float sc[4];
        float mx = -1e30f;
#pragma unroll
        for (int jj = 0; jj < 4; ++jj) {
            const float4* kp = (const float4*)&sqkv[(la * 4 + jj) * 100 + 32 + h * 8];
            sc[jj] = dot8(q0, q1, kp[0], kp[1]) * scale;
            mx = fmaxf(mx, sc[jj]);
        }
        float den = 0.f;
#pragma unroll
        for (int jj = 0; jj < 4; ++jj) { sc[jj] = __expf(sc[jj] - mx); den += sc[jj]; }
        float inv = 1.f / den;
        float a[8];
#pragma unroll
        for (int dd = 0; dd < 8; ++dd) a[dd] = 0.f;
#pragma unroll
        for (int jj = 0; jj < 4; ++jj) {
            const float4* vp = (const float4*)&sqkv[(la * 4 + jj) * 100 + 64 + h * 8];
            float4 v0 = vp[0], v1 = vp[1];
            float wgt = sc[jj];
            a[0] += wgt * v0.x;  a[1] += wgt * v0.y;
            a[2] += wgt * v0.z;  a[3] += wgt * v0.w;
            a[4] += wgt * v1.x;  a[5] += wgt * v1.y;
            a[6] += wgt * v1.z;  a[7] += wgt * v1.w;
        }
#pragma unroll
        for (int dd = 0; dd < 8; ++dd) so[la * 4 + ia][h * 8 + dd] = a[dd] * inv;
    }
    __syncthreads();

    {
        float orow[32];
#pragma unroll
        for (int k = 0; k < 32; ++k) orow[k] = so[r][k];
#pragma unroll
        for (int i = 0; i < 8; ++i) {
            int c = i * 4 + cg;
            const float4* wr4 = (const float4*)&w_out[c * 32];
            float acc = b_out[c] + xr[c];
#pragma unroll
            for (int k4 = 0; k4 < 8; ++k4) {
                float4 wv = wr4[k4];
                acc += orow[k4 * 4 + 0] * wv.x + orow[k4 * 4 + 1] * wv.y +
                       orow[k4 * 4 + 2] * wv.z + orow[k4 * 4 + 3] * wv.w;
            }
            sqkv[r * 100 + c] = acc;
        }
    }
    __syncthreads();

    if (tid < 64) {
        float mu = 0.f;
#pragma unroll
        for (int c = 0; c < 32; ++c) mu += sqkv[tid * 100 + c];
        mu *= (1.f / 32.f);
        float var = 0.f;
#pragma unroll
        for (int c = 0; c < 32; ++c) { float d = sqkv[tid * 100 + c] - mu; var += d * d; }
        var *= (1.f / 32.f);
        smean2[tid] = mu;
        srstd2[tid] = rsqrtf(var + LN_EPS);
    }
    __syncthreads();

    for (int pass = 0; pass < 2; ++pass) {
        int idx = pass * 256 + tid;      // 512 = 16 lo x 32 c
        int loo = idx >> 5, c = idx & 31;
        float acc = 0.f;
#pragma unroll
        for (int ss = 0; ss < 4; ++ss) {
            int rr = loo * 4 + ss;
            acc += (sqkv[rr * 100 + c] - smean2[rr]) * srstd2[rr];
        }
        float mval = 0.25f * acc * ln_g[c] + ln_b[c];
        m_out[(b * 64 + l0 + loo) * 32 + c] = mval;
        smv[loo][c] = mval * mval;
    }
    __syncthreads();

    if (tid < 16) {
        float sum = 0.f;
#pragma unroll
        for (int c = 0; c < 32; ++c) sum += smv[tid][c];
        nrm_out[b * 64 + l0 + tid] = sqrtf(sum);
    }
}

// ---------------------------------------------------------------------------
// Kernel 3 (v3): factorized outer-product + proj + LN + SiLU + transpose
// feat[b,i,j,cp] = (T_i[cp]·m_j)/(|m_i||m_j|) + pb;  T_i = pw·m_i
// 512 blocks (b x 8 i-chunks of 8) x 256 threads -> 2 blocks/CU.
// ---------------------------------------------------------------------------
__global__ __launch_bounds__(256) void k_pair(
    const float* __restrict__ m, const float* __restrict__ nrm,
    const float* __restrict__ pw, const float* __restrict__ pb,
    const float* __restrict__ pg, const float* __restrict__ pbeta,
    float* __restrict__ out)
{
    __shared__ float smj[64][36];       // stride 36 -> rows 16B-aligned
    __shared__ float sT[8 * 520];       // [il][rem], stride 520 (16B-aligned)
    __shared__ float snj[64];
    __shared__ float sbias[16], sgam[16], sbet[16];

    const int bx = blockIdx.x;          // 64 b x 8 i-chunks
    const int b  = bx >> 3;
    const int i0 = (bx & 7) * 8;
    const int tid = threadIdx.x;
    const int lane = tid & 63, w = tid >> 6;

    // preload this thread's two pw rem-rows into regs (global, coalesced, L2-hot)
    const int rem0 = lane + 128 * w;    // rem = cp*32+d, 0..511 over (w,lane)
    const int rem1 = rem0 + 64;
    const float* pw0 = pw + (rem0 >> 5) * 1024 + (rem0 & 31);
    const float* pw1 = pw + (rem1 >> 5) * 1024 + (rem1 & 31);
    float w0[32], w1[32];
#pragma unroll
    for (int c = 0; c < 32; ++c) { w0[c] = pw0[c * 32]; w1[c] = pw1[c * 32]; }

    const float* mb = m + b * 2048;
    for (int n = tid; n < 2048; n += 256) smj[n >> 5][n & 31] = mb[n];
    if (tid < 64) snj[tid] = nrm[b * 64 + tid];
    if (tid < 16) {
        sbias[tid] = pb[tid];
        sgam[tid]  = pg[tid];
        sbet[tid]  = pbeta[tid];
    }
    __syncthreads();

    // T phase: every thread computes T[il][rem0], T[il][rem1] for il = 0..7
#pragma unroll
    for (int il = 0; il < 8; ++il) {
        const float4* mr4 = (const float4*)&smj[i0 + il][0];  // b128 broadcast
        float a0 = 0.f, a1 = 0.f;
#pragma unroll
        for (int c4 = 0; c4 < 8; ++c4) {
            float4 mv = mr4[c4];
            a0 += mv.x * w0[c4 * 4 + 0] + mv.y * w0[c4 * 4 + 1] +
                  mv.z * w0[c4 * 4 + 2] + mv.w * w0[c4 * 4 + 3];
            a1 += mv.x * w1[c4 * 4 + 0] + mv.y * w1[c4 * 4 + 1] +
                  mv.z * w1[c4 * 4 + 2] + mv.w * w1[c4 * 4 + 3];
        }
        sT[il * 520 + rem0] = a0;       // lane-distinct banks, conflict-free
        sT[il * 520 + rem1] = a1;
    }
    __syncthreads();

    // out phase: lane = j; wave w handles il = 2w, 2w+1
    const int j = lane;
    float mj[32];
    {
        const float4* mjp = (const float4*)&smj[j][0];
#pragma unroll
        for (int d4 = 0; d4 < 8; ++d4) {
            float4 t = mjp[d4];
            mj[d4 * 4 + 0] = t.x;  mj[d4 * 4 + 1] = t.y;
            mj[d4 * 4 + 2] = t.z;  mj[d4 * 4 + 3] = t.w;
        }
    }
    const float nj = snj[j];

#pragma unroll
    for (int q = 0; q < 2; ++q) {
        const int il = w * 2 + q;
        const int ig = i0 + il;
        const float invn = 1.f / fmaxf(snj[ig] * nj, 1e-6f);
        float f[16];
#pragma unroll
        for (int cp = 0; cp < 16; ++cp) {
            const float4* tr = (const float4*)&sT[il * 520 + cp * 32]; // b128 bcast
            float acc = 0.f;
#pragma unroll
            for (int d4 = 0; d4 < 8; ++d4) {
                float4 tv = tr[d4];
                acc += tv.x * mj[d4 * 4 + 0] + tv.y * mj[d4 * 4 + 1] +
                       tv.z * mj[d4 * 4 + 2] + tv.w * mj[d4 * 4 + 3];
            }
            f[cp] = acc * invn + sbias[cp];
        }
        float mu = 0.f;
#pragma unroll
        for (int cp = 0; cp < 16; ++cp) mu += f[cp];
        mu *= (1.f / 16.f);
        float var = 0.f;
#pragma unroll
        for (int cp = 0; cp < 16; ++cp) { float d = f[cp] - mu; var += d * d; }
        var *= (1.f / 16.f);
        const float rstd = rsqrtf(var + LN_EPS);
#pragma unroll
        for (int cp = 0; cp < 16; ++cp) {
            float v = (f[cp] - mu) * rstd * sgam[cp] + sbet[cp];
            float sl = v / (1.f + __expf(-v));
            out[((b * 16 + cp) * 64 + ig) * 64 + j] = sl;
        }
    }
}

// ---------------------------------------------------------------------------
extern "C" void kernel_launch(void* const* d_in, const int* in_sizes, int n_in,
                              void* d_out, int out_size, void* d_ws, size_t ws_size,
                              hipStream_t stream) {
    const float* ctcf  = (const float*)d_in[0];
    const float* hac   = (const float*)d_in[1];
    const float* me1   = (const float*)d_in[2];
    const float* me3   = (const float*)d_in[3];
    const float* ew    = (const float*)d_in[4];
    const float* ebias = (const float*)d_in[5];
    const float* pe    = (const float*)d_in[6];
    const float* riw   = (const float*)d_in[7];
    const float* rib   = (const float*)d_in[8];
    const float* row_  = (const float*)d_in[9];
    const float* rob   = (const float*)d_in[10];
    const float* rlg   = (const float*)d_in[11];
    const float* rlb   = (const float*)d_in[12];
    const float* ciw   = (const float*)d_in[13];
    const float* cib   = (const float*)d_in[14];
    const float* cow   = (const float*)d_in[15];
    const float* cob   = (const float*)d_in[16];
    const float* clg   = (const float*)d_in[17];
    const float* clb   = (const float*)d_in[18];
    const float* pw    = (const float*)d_in[19];
    const float* pb    = (const float*)d_in[20];
    const float* pg    = (const float*)d_in[21];
    const float* pbt   = (const float*)d_in[22];

    float* out = (float*)d_out;

    // msaR (2 MB) borrows d_out (16 MB f32): fully consumed by k_col before
    // k_pair writes out (serial stream). m + norms in ws (~528 KB).
    float* msaR = (float*)d_out;
    float* mbuf = (float*)d_ws;                  // 64*64*32 floats
    float* nbuf = mbuf + 64 * 64 * 32;           // 64*64 floats

    k_row<<<256, 256, 0, stream>>>(ctcf, hac, me1, me3, ew, ebias, pe,
                                   riw, rib, row_, rob, rlg, rlb, msaR);
    k_col<<<256, 256, 0, stream>>>(msaR, ciw, cib, cow, cob, clg, clb,
                                   mbuf, nbuf);
    k_pair<<<512, 256, 0, stream>>>(mbuf, nbuf, pw, pb, pg, pbt, out);
}